// Round 5
// baseline (5001.055 us; speedup 1.0000x reference)
//
#include <hip/hip_runtime.h>
#include <hip/hip_bf16.h>

typedef __hip_bfloat16 bf16;
typedef unsigned short u16;
typedef unsigned int u32;
typedef __attribute__((ext_vector_type(8))) short short8;
typedef __attribute__((ext_vector_type(4))) float f32x4;

#define B_ 50
#define L_ 1024
#define H_ 512
#define N_ 512
#define BL_ 51200        // B_*L_
#define HBL_ 26214400    // H_*BL_
#define KROW_ 1088       // L_ + 64 zero-pad front
#define PI_F 3.14159265358979323846f
#define MARK_BF16 0x3F803F80u
#define KRSW_ 1112       // u16 stride of one reversed-K copy
#define CONV_LDS_BYTES 151040  // (65536 + 8*1112 + 1088) u16 * 2

// kFF2 LDS layout (bytes): wa 65536 | yt 65536 | res 9216 | bias 2048 | red 2048
#define FF_RES 131072
#define FF_SB  140288
#define FF_RED 142336
#define FF2_LDS_BYTES 144384
// swizzled byte addr within wa/yt: 128B rows, XOR on 16B-slot bits
#define WAB(kc,m,cb) ((((kc)<<13) + ((m)<<7)) + ((cb) ^ (((((m)^(kc))&7))<<4)))
#define YTB(kc,n,cb) (65536 + (((kc)<<13) + ((n)<<7)) + ((cb) ^ (((((n)&7)^((n)>>3)^(kc))&7)<<4)))

__device__ __forceinline__ float u2f(u16 u){ union{u32 i; float f;} v; v.i = ((u32)u)<<16; return v.f; }
__device__ __forceinline__ u16  f2u(float x){ bf16 b = __float2bfloat16(x); return *(u16*)&b; }

__device__ __forceinline__ float ld_in(const void* p, int i, bool bff){
  if (bff){ u16 v = ((const u16*)p)[i]; union{u32 a; float f;} u; u.a = ((u32)v)<<16; return u.f; }
  return ((const float*)p)[i];
}

// fast tanh: 1 - 2/(e^{2|x|}+1), sign-restored. ~1e-6 abs err, way under bf16 quantum.
__device__ __forceinline__ float tanh_f(float x){
  float ax = fabsf(x);
  float e = __expf(2.f*ax);
  float r = 1.f - 2.f/(e + 1.f);
  return copysignf(r, x);
}

__device__ __forceinline__ float gelu_f(float x){
  float t = tanh_f(0.7978845608028654f*(x + 0.044715f*x*x*x));
  return 0.5f*x*(1.0f + t);
}

// ---------------- kernel synthesis ----------------
__global__ __launch_bounds__(256) void kV(float* __restrict__ Vre, float* __restrict__ Vim){
  int idx = blockIdx.x*256 + threadIdx.x;        // < N_*L_
  int n = idx >> 10, l = idx & 1023;
  int ph = (n*l) % 2000;                         // exact phase reduction
  float ang = (float)ph * (PI_F/1000.f);
  float mag = expf(-5e-4f*(float)l);
  float s, c;
  sincosf(ang, &s, &c);
  Vre[idx] = mag*c;
  Vim[idx] = mag*s;
}

__global__ __launch_bounds__(256) void kX(const u32* __restrict__ mk,
                                          const void* __restrict__ Cre, const void* __restrict__ Cim,
                                          float* __restrict__ Xre, float* __restrict__ Xim){
  const bool bff = (*mk == MARK_BF16);
  int idx = blockIdx.x*256 + threadIdx.x;        // < 6*H_*N_
  int n = idx & (N_-1);
  float ar = -0.5f, ai = PI_F*(float)n;
  float ex = expf(-5e-4f);
  float s, c;
  sincosf(1e-3f*ai, &s, &c);
  float dre = ex*c - 1.f;
  float dim = ex*s;
  float inv = 1.f/(ar*ar + ai*ai);
  float dBre = (dre*ar + dim*ai)*inv;
  float dBim = (dim*ar - dre*ai)*inv;
  float cr = ld_in(Cre, idx, bff), ci = ld_in(Cim, idx, bff);
  Xre[idx] = cr*dBre - ci*dBim;
  Xim[idx] = cr*dBim + ci*dBre;
}

// K -> bf16, padded. 8 rows x 2 cols/thread, 768 blocks (3/CU) for latency hiding.
__global__ __launch_bounds__(256) void kK(const float* __restrict__ Xre, const float* __restrict__ Xim,
                                          const float* __restrict__ Vre, const float* __restrict__ Vim,
                                          u16* __restrict__ Kbp){
  __shared__ float sxr[8*128], sxi[8*128];
  int kh0 = blockIdx.x*8;
  int l0 = blockIdx.y*512 + threadIdx.x;         // col A; col B = l0+256
  float accA[8], accB[8];
  #pragma unroll
  for (int t=0;t<8;++t){ accA[t]=0.f; accB[t]=0.f; }
  for (int nc=0; nc<4; ++nc){
    if (nc) __syncthreads();
    #pragma unroll
    for (int q=0;q<4;++q){
      int e = q*256 + threadIdx.x;               // < 1024
      int r = e >> 7, c = e & 127;
      sxr[e] = Xre[(kh0+r)*N_ + nc*128 + c];
      sxi[e] = Xim[(kh0+r)*N_ + nc*128 + c];
    }
    __syncthreads();
    for (int n4=0;n4<32;++n4){
      int nb = (nc*128 + n4*4)*L_ + l0;
      float vrA[4], viA[4], vrB[4], viB[4];
      #pragma unroll
      for (int k=0;k<4;++k){
        vrA[k] = Vre[nb + k*L_];       viA[k] = Vim[nb + k*L_];
        vrB[k] = Vre[nb + k*L_ + 256]; viB[k] = Vim[nb + k*L_ + 256];
      }
      #pragma unroll
      for (int t=0;t<8;++t){
        f32x4 xr = *(const f32x4*)&sxr[t*128 + n4*4];
        f32x4 xi = *(const f32x4*)&sxi[t*128 + n4*4];
        float a = accA[t], b = accB[t];
        #pragma unroll
        for (int k=0;k<4;++k){
          a += xr[k]*vrA[k] - xi[k]*viA[k];
          b += xr[k]*vrB[k] - xi[k]*viB[k];
        }
        accA[t] = a; accB[t] = b;
      }
    }
  }
  #pragma unroll
  for (int t=0;t<8;++t){
    Kbp[(kh0+t)*KROW_ + 64 + l0]       = f2u(2.f*accA[t]);
    Kbp[(kh0+t)*KROW_ + 64 + l0 + 256] = f2u(2.f*accB[t]);
  }
  if (blockIdx.y == 0 && threadIdx.x < 64){
    #pragma unroll
    for (int t=0;t<8;++t) Kbp[(kh0+t)*KROW_ + threadIdx.x] = 0;
  }
}

// W_feed [k][m] f32 -> Wbt [m][k] bf16
__global__ __launch_bounds__(256) void kWb(const u32* __restrict__ mk,
                                           const void* __restrict__ W, u16* __restrict__ Wbt){
  const bool bff = (*mk == MARK_BF16);
  int idx = blockIdx.x*256 + threadIdx.x;        // < 262144
  int k = idx >> 9, m = idx & 511;
  Wbt[m*512 + k] = f2u(ld_in(W, k*512 + m, bff));
}

// ---------------- embedding ----------------
__global__ __launch_bounds__(256) void kEmbed(const u32* __restrict__ mk,
                                              const void* __restrict__ x, const void* __restrict__ W,
                                              const void* __restrict__ be, u16* __restrict__ out){
  const bool bff = (*mk == MARK_BF16);
  int t = blockIdx.x*256 + threadIdx.x;          // < HBL_/4
  int e = t*4;
  int h = e / BL_;
  int col = e - h*BL_;
  float w = ld_in(W, h, bff), bb = ld_in(be, h, bff);
  ushort4 o;
  o.x = f2u(ld_in(x, col+0, bff)*w + bb);
  o.y = f2u(ld_in(x, col+1, bff)*w + bb);
  o.z = f2u(ld_in(x, col+2, bff)*w + bb);
  o.w = f2u(ld_in(x, col+3, bff)*w + bb);
  *(ushort4*)(out + e) = o;
}

// ---------------- zero Z + loss accumulator ----------------
__global__ __launch_bounds__(256) void kZero(uint4* __restrict__ Z, float* __restrict__ lossAcc){
  int t = blockIdx.x*256 + threadIdx.x;          // < HBL_*2/16
  Z[t] = make_uint4(0u,0u,0u,0u);
  if (t == 0) *lossAcc = 0.f;
}

// ---------------- LayerNorm over h; vectorized uint4 loads, col-octet/thread ----------------
__global__ __launch_bounds__(256) void kLN2(const u32* __restrict__ mk,
                                            const u16* __restrict__ U, const u16* __restrict__ U2,
                                            const void* __restrict__ g, const void* __restrict__ bb,
                                            int off, u16* __restrict__ Vout){
  const bool bff = (*mk == MARK_BF16);
  __shared__ float rs[32][64], rq[32][64], ms[64], rr[64], gs[512], bs[512];
  int c8 = threadIdx.x & 7;                      // col-octet within 64-col tile
  int ty = threadIdx.x >> 3;                     // 0..31
  int colb = blockIdx.x*64 + c8*8;
  // stage g/b
  for (int i = threadIdx.x; i < 512; i += 256){
    gs[i] = ld_in(g, off+i, bff);
    bs[i] = ld_in(bb, off+i, bff);
  }
  float s8[8], q8[8];
  #pragma unroll
  for (int j=0;j<8;++j){ s8[j]=0.f; q8[j]=0.f; }
  for (int p=0;p<16;++p){
    int h = ty + p*32;
    uint4 uv = *(const uint4*)(U + (size_t)h*BL_ + colb);
    const u16* pu = (const u16*)&uv;
    float xv[8];
    #pragma unroll
    for (int j=0;j<8;++j) xv[j] = u2f(pu[j]);
    if (U2){
      uint4 uv2 = *(const uint4*)(U2 + (size_t)h*BL_ + colb);
      const u16* p2 = (const u16*)&uv2;
      #pragma unroll
      for (int j=0;j<8;++j) xv[j] += u2f(p2[j]);
    }
    #pragma unroll
    for (int j=0;j<8;++j){ s8[j] += xv[j]; q8[j] += xv[j]*xv[j]; }
  }
  *(f32x4*)&rs[ty][c8*8]   = (f32x4){s8[0],s8[1],s8[2],s8[3]};
  *(f32x4*)&rs[ty][c8*8+4] = (f32x4){s8[4],s8[5],s8[6],s8[7]};
  *(f32x4*)&rq[ty][c8*8]   = (f32x4){q8[0],q8[1],q8[2],q8[3]};
  *(f32x4*)&rq[ty][c8*8+4] = (f32x4){q8[4],q8[5],q8[6],q8[7]};
  __syncthreads();
  if (threadIdx.x < 64){
    int c = threadIdx.x;
    float st = 0.f, qt = 0.f;
    #pragma unroll 8
    for (int t2=0;t2<32;++t2){ st += rs[t2][c]; qt += rq[t2][c]; }
    float mean = st*(1.f/512.f);
    float var  = qt*(1.f/512.f) - mean*mean;
    ms[c] = mean;
    rr[c] = rsqrtf(var + 1e-5f);
  }
  __syncthreads();
  float mean8[8], rstd8[8];
  #pragma unroll
  for (int j=0;j<8;++j){ mean8[j] = ms[c8*8+j]; rstd8[j] = rr[c8*8+j]; }
  for (int p=0;p<16;++p){
    int h = ty + p*32;
    uint4 uv = *(const uint4*)(U + (size_t)h*BL_ + colb);
    const u16* pu = (const u16*)&uv;
    float xv[8];
    #pragma unroll
    for (int j=0;j<8;++j) xv[j] = u2f(pu[j]);
    if (U2){
      uint4 uv2 = *(const uint4*)(U2 + (size_t)h*BL_ + colb);
      const u16* p2 = (const u16*)&uv2;
      #pragma unroll
      for (int j=0;j<8;++j) xv[j] += u2f(p2[j]);
    }
    float gv = gs[h], bv = bs[h];
    union { uint4 v; u16 s[8]; } ob;
    #pragma unroll
    for (int j=0;j<8;++j) ob.s[j] = f2u((xv[j]-mean8[j])*rstd8[j]*gv + bv);
    *(uint4*)(Vout + (size_t)h*BL_ + colb) = ob.v;
  }
}

// ---------------- MFMA causal conv, one block per h ----------------
__global__ __launch_bounds__(512, 2) void kConvM(const u32* __restrict__ mk,
                                              const u16* __restrict__ V, const u16* __restrict__ Kb,
                                              const void* __restrict__ Dv, int dOff,
                                              const u16* __restrict__ U,
                                              u16* __restrict__ Y, int skip, int doGelu){
  extern __shared__ u16 lds[];
  u16* sV  = lds;                    // 64 rows x 1024 u16, swizzled (131072 B)
  u16* sKR = lds + 65536;            // 8 copies x KRSW_ (17792 B)
  u16* sKt = lds + 65536 + 8*KRSW_;  // Kpad row tmp (2176 B)
  const bool bff = (*mk == MARK_BF16);
  int h = blockIdx.x;
  int tid = threadIdx.x;
  const u16* Kbh = Kb + h*KROW_;
  for (int s = tid; s < 1088; s += 512) sKt[s] = Kbh[s];
  __syncthreads();
  #pragma unroll
  for (int p = 0; p < 8; ++p){
    for (int s = tid; s < KRSW_; s += 512){
      int idx = 1087 - s - p;
      sKR[p*KRSW_ + s] = (idx >= 0) ? sKt[idx] : (u16)0;
    }
  }
  {
    const u16* Vh = V + (size_t)h*(B_*L_);
    #pragma unroll
    for (int q = 0; q < 16; ++q){
      int chunk = q*512 + tid;        // 0..8191 16B-chunks
      int r = chunk >> 7;
      int c16 = chunk & 127;
      uint4 dval = *(const uint4*)(Vh + r*L_ + c16*8);
      u32 byte = ((u32)r << 11) + ((u32)c16 << 4);
      byte ^= ((u32)(r & 7) << 4);
      *(uint4*)((char*)sV + byte) = dval;
    }
  }
  __syncthreads();
  int wv = tid >> 6, lane = tid & 63;
  int nl = lane & 15, quad = lane >> 4;
  float Dh = ld_in(Dv, dOff + h, bff);
  #pragma unroll 1
  for (int cc = 0; cc < 2; ++cc){
    int c_out = cc ? (15 - wv) : wv;
    f32x4 acc[4][4];
    #pragma unroll
    for (int mt=0;mt<4;++mt){
      #pragma unroll
      for (int nt=0;nt<4;++nt) acc[mt][nt] = (f32x4){0.f,0.f,0.f,0.f};
    }
    for (int ci = 0; ci <= c_out; ++ci){
      int d = c_out - ci;
      short8 a0[4], a1[4], b0[4], b1[4];
      #pragma unroll
      for (int mt=0;mt<4;++mt){
        int r = mt*16 + nl;
        u32 msk = (u32)(r & 7) << 4;
        u32 base = ((u32)r << 11) + (u32)((ci*64 + quad*8) << 1);
        a0[mt] = *(const short8*)((const char*)sV + (base ^ msk));
        a1[mt] = *(const short8*)((const char*)sV + ((base + 64u) ^ msk));
      }
      #pragma unroll
      for (int nt=0;nt<4;++nt){
        int i = nt*16 + nl;
        int t0 = 1023 - d*64 - i + quad*8;     // in [0,1054]
        const u16* bp = sKR + (t0 & 7)*KRSW_ + (t0 & ~7);
        b0[nt] = *(const short8*)bp;
        b1[nt] = *(const short8*)(bp + 32);
      }
      #pragma unroll
      for (int mt=0;mt<4;++mt){
        #pragma unroll
        for (int nt=0;nt<4;++nt){
          acc[mt][nt] = __builtin_amdgcn_mfma_f32_16x16x32_bf16(a0[mt], b0[nt], acc[mt][nt], 0,0,0);
          acc[mt][nt] = __builtin_amdgcn_mfma_f32_16x16x32_bf16(a1[mt], b1[nt], acc[mt][nt], 0,0,0);
        }
      }
    }
    #pragma unroll
    for (int mt=0;mt<4;++mt){
      #pragma unroll
      for (int reg=0;reg<4;++reg){
        int b = mt*16 + quad*4 + reg;
        if (b < B_){
          #pragma unroll
          for (int nt=0;nt<4;++nt){
            int col = c_out*64 + nt*16 + nl;
            u32 vb = (((u32)b << 11) + ((u32)col << 1)) ^ ((u32)(b & 7) << 4);
            float vv = u2f(*(const u16*)((const char*)sV + vb));
            size_t gi = (size_t)(h*B_ + b)*L_ + col;
            float y = tanh_f(acc[mt][nt][reg] + vv*Dh);
            if (skip) y += u2f(U[gi]);
            if (doGelu) y = gelu_f(y);
            Y[gi] = f2u(y);
          }
        }
      }
    }
  }
}

// ---------------- MFMA FF v3: per block = 64-n stripe x ALL 512 m ----------------
// Z[m,n] = gelu(sum_k W_feed[k,m]*Y[k,n] + bias[m]).
// Y tile transposed ONCE into swizzled LDS; A and B fragments both read from
// LDS per kc (NO register B-cache: 128+ VGPR demand under launch_bounds(512,2)
// demoted it to scratch -> 280 MB of hidden HBM traffic in R4).
// Results staged in LDS, flushed as full-128B-line uint4 stores.
__global__ __launch_bounds__(512, 2) void kFF2(const u32* __restrict__ mk,
                                            const u16* __restrict__ Yin, const u16* __restrict__ Wbt,
                                            const void* __restrict__ bias, u16* __restrict__ Zout,
                                            const u16* __restrict__ Zold, float* __restrict__ lossAcc,
                                            int doLoss){
  extern __shared__ char ldsF[];
  u16* res  = (u16*)(ldsF + FF_RES);      // [64][72] u16
  float* sb = (float*)(ldsF + FF_SB);     // bias[512]
  float* red= (float*)(ldsF + FF_RED);    // loss reduction[512]
  const bool bff = (*mk == MARK_BF16);
  int n0g = blockIdx.x*64;
  int tid = threadIdx.x;

  sb[tid & 511] = ld_in(bias, tid & 511, bff);

  int rW = tid >> 3, kq = tid & 7;
  uint4 wreg[8];
  {
    const u16* wp = Wbt + (size_t)rW*512 + kq*64;    // W chunk mc=0
    #pragma unroll
    for (int i=0;i<8;++i) wreg[i] = *(const uint4*)(wp + i*8);
  }

  // transpose Y (64 n x 512 k) into yt, swizzled
  {
    int rY = tid >> 3, q3 = tid & 7;
    #pragma unroll
    for (int kc=0;kc<8;++kc){
      const u16* yp = Yin + (size_t)(kc*64 + rY)*BL_ + n0g + q3*8;
      uint4 v = *(const uint4*)yp;
      const u16* pv = (const u16*)&v;
      int nb = q3*8;
      #pragma unroll
      for (int j=0;j<8;++j) *(u16*)(ldsF + YTB(kc, nb+j, rY*2)) = pv[j];
    }
  }
  // write W(0) into wa, swizzled
  #pragma unroll
  for (int i=0;i<8;++i) *(uint4*)(ldsF + WAB(kq, rW, i*16)) = wreg[i];
  __syncthreads();

  int wv = tid >> 6, lane = tid & 63;
  int nl = lane & 15, quad = lane >> 4;
  int mt = wv >> 1, ntb = (wv & 1)*2;
  int mrow = mt*16 + nl;
  int nr0 = ntb*16 + nl, nr1 = nr0 + 16;
  // prefetch W(1)
  {
    const u16* wp = Wbt + (size_t)64*512 + (size_t)rW*512 + kq*64;
    #pragma unroll
    for (int i=0;i<8;++i) wreg[i] = *(const uint4*)(wp + i*8);
  }

  float ls = 0.f;
  int frow = tid >> 3, fcol = (tid & 7)*8;

  #pragma unroll 1
  for (int mc=0; mc<8; ++mc){
    f32x4 acc0 = (f32x4){0.f,0.f,0.f,0.f};
    f32x4 acc1 = (f32x4){0.f,0.f,0.f,0.f};
    #pragma unroll
    for (int kc=0;kc<8;++kc){
      short8 a0  = *(const short8*)(ldsF + WAB(kc, mrow, quad*16));
      short8 a1  = *(const short8*)(ldsF + WAB(kc, mrow, 64 + quad*16));
      short8 b00 = *(const short8*)(ldsF + YTB(kc, nr0, quad*16));
      short8 b01 = *(const short8*)(ldsF + YTB(kc, nr0, 64 + quad*16));
      short8 b10 = *(const short8*)(ldsF + YTB(kc, nr1, quad*16));
      short8 b11 = *(const short8*)(ldsF + YTB(kc, nr1, 64 + quad*16));
      acc0 = __builtin_amdgcn_mfma_f32_16x16x32_bf16(a0, b00, acc0, 0,0,0);
      acc0 = __builtin_amdgcn_mfma_f32_16x16x32_bf16(a1, b01, acc0, 0,0,0);
      acc1 = __builtin_amdgcn_mfma_f32_16x16x32_bf16(a0, b10, acc1, 0,0,0);
      acc1 = __builtin_amdgcn_mfma_f32_16x16x32_bf16(a1, b11, acc1, 0,0,0);
    }
    // epilogue -> res (per-wave disjoint regions)
    #pragma unroll
    for (int reg=0;reg<4;++reg){
      int mloc = mt*16 + quad*4 + reg;
      float bv = sb[mc*64 + mloc];
      res[mloc*72 + ntb*16 + nl]      = f2u(gelu_f(acc0[reg] + bv));
      res[mloc*72 + ntb*16 + nl + 16] = f2u(gelu_f(acc1[reg] + bv));
    }
    __syncthreads();   // (a) all MFMA reads of wa done; res complete
    if (mc < 7){
      #pragma unroll
      for (int i=0;i<8;++i) *(uint4*)(ldsF + WAB(kq, rW, i*16)) = wreg[i];
    }
    // flush: one full 128B line per 8-lane group
    {
      size_t zoff = (size_t)(mc*64 + frow)*BL_ + n0g + fcol;
      uint4 v = *(const uint4*)&res[frow*72 + fcol];
      if (doLoss){
        uint4 zo = *(const uint4*)(Zold + zoff);
        const u16* pv = (const u16*)&v;
        const u16* po = (const u16*)&zo;
        #pragma unroll
        for (int j=0;j<8;++j){ float d = u2f(pv[j]) - u2f(po[j]); ls += d*d; }
      }
      *(uint4*)(Zout + zoff) = v;
    }
    if (mc < 6){
      const u16* wp = Wbt + (size_t)(mc+2)*64*512 + (size_t)rW*512 + kq*64;
      #pragma unroll
      for (int i=0;i<8;++i) wreg[i] = *(const uint4*)(wp + i*8);
    }
    __syncthreads();   // (b) wa(mc+1) staged; res free for next epilogue
  }
  if (doLoss){
    red[tid] = ls;
    __syncthreads();
    for (int off=256; off>0; off>>=1){
      if (tid < off) red[tid] += red[tid+off];
      __syncthreads();
    }
    if (tid==0) atomicAdd(lossAcc, red[0]);
  }
}

// ---------------- scalars: loss + n_deq (f32 out) ----------------
__global__ void kScalars(const float* __restrict__ lossAcc, float* __restrict__ outp){
  if (threadIdx.x == 0 && blockIdx.x == 0){
    outp[500] = *lossAcc * (1.f/26214400.f);
    outp[26214901] = 8.0f;
  }
}

// ---------------- transpose [H,B,L] bf16 -> out[b,l,h] f32 ----------------
__global__ __launch_bounds__(256) void kTrans(const u16* __restrict__ Z, float* __restrict__ out){
  __shared__ u16 st[64][68];
  int b = blockIdx.z, h0 = blockIdx.y*64, l0 = blockIdx.x*64;
  int tid = threadIdx.x;
  int r = tid >> 2, q = tid & 3;
  const u16* src = Z + ((h0+r)*B_ + b)*L_ + l0 + q*16;
  #pragma unroll
  for (int c=0; c<4; ++c){
    ushort4 v = *(const ushort4*)(src + c*4);
    st[r][q*16 + c*4 + 0] = v.x;
    st[r][q*16 + c*4 + 1] = v.y;
    st[r][q*16 + c*4 + 2] = v.z;
    st[r][q*16 + c*4 + 3] = v.w;
  }
  __syncthreads();
  int i = tid & 63;
  int j0 = tid >> 6;
  for (int jj = j0; jj < 64; jj += 4){
    out[(size_t)(b*L_ + l0 + jj)*H_ + h0 + i] = u2f(st[i][jj]);
  }
}

// ---------------- mean over l ----------------
__global__ __launch_bounds__(256) void kMeanL(const u16* __restrict__ Z, float* __restrict__ Hb){
  int lane = threadIdx.x & 63;
  int ridx = blockIdx.x*4 + (threadIdx.x >> 6);  // = ho*B_+b
  const u16* row = Z + (size_t)ridx*L_;
  float s = 0.f;
  for (int ii=lane; ii<L_; ii+=64) s += u2f(row[ii]);
  for (int off=32; off>0; off>>=1) s += __shfl_down(s, off, 64);
  if (lane==0){
    int ho = ridx / B_, b = ridx - ho*B_;
    Hb[b*H_ + ho] = s*(1.f/1024.f);
  }
}

__global__ __launch_bounds__(256) void kLogits(const u32* __restrict__ mk,
                                               const float* __restrict__ Hb, const void* __restrict__ Wfc,
                                               const void* __restrict__ bfc, float* __restrict__ outp){
  const bool bff = (*mk == MARK_BF16);
  int t = blockIdx.x*256 + threadIdx.x;
  if (t < 500){
    int b = t/10, c = t - (t/10)*10;
    float s = ld_in(bfc, c, bff);
    for (int ho=0; ho<H_; ++ho) s += Hb[b*H_+ho]*ld_in(Wfc, ho*10+c, bff);
    outp[t] = s;
  }
}

extern "C" void kernel_launch(void* const* d_in, const int* in_sizes, int n_in,
                              void* d_out, int out_size, void* d_ws, size_t ws_size,
                              hipStream_t stream) {
  (void)in_sizes; (void)n_in; (void)out_size; (void)ws_size;
  const void* x      = d_in[0];
  const void* W_emb  = d_in[1];
  const void* b_emb  = d_in[2];
  const void* C_re   = d_in[3];
  const void* C_im   = d_in[4];
  const void* Dp     = d_in[5];
  const void* ln_g   = d_in[6];
  const void* ln_b   = d_in[7];
  const void* W_feed = d_in[8];
  const void* b_feed = d_in[9];
  const void* W_fc   = d_in[10];
  const void* b_fc   = d_in[11];
  const u32* mk = (const u32*)d_in[5];
  float* outp = (float*)d_out;

  static int s_attr = 0;
  if (!s_attr){
    hipFuncSetAttribute(reinterpret_cast<const void*>(kConvM),
                        hipFuncAttributeMaxDynamicSharedMemorySize, CONV_LDS_BYTES);
    hipFuncSetAttribute(reinterpret_cast<const void*>(kFF2),
                        hipFuncAttributeMaxDynamicSharedMemorySize, FF2_LDS_BYTES);
    s_attr = 1;
  }

  // ws: Kbp bf16[6*512*1088] | Zb | T1 | T2 (bf16 HBL each) | Hbar f32 | lossAcc | Wbt (~164.6 MB)
  u16* Kbp = (u16*)d_ws;
  u16* Zb  = Kbp + 6*H_*KROW_;
  u16* T1  = Zb + HBL_;
  u16* T2  = T1 + HBL_;
  float* Hbar = (float*)(T2 + HBL_);
  float* lossAcc = Hbar + 25600;
  u16* Wbt = (u16*)(Hbar + 25604);               // 0.5 MB, 16B-aligned
  // d_out-resident scratch: X0 (bf16 HBL, bytes 0..52.4MB); dead before final writes.
  u16* X0  = (u16*)d_out;
  // phase-A f32 scratch carved from T1
  float* Vre = (float*)T1;
  float* Vim = Vre + N_*L_;
  float* Xre = Vim + N_*L_;
  float* Xim = Xre + 6*H_*N_;

  // 1) kernels K (bf16 padded) + W transpose
  kV<<<2048, 256, 0, stream>>>(Vre, Vim);
  kX<<<6144, 256, 0, stream>>>(mk, C_re, C_im, Xre, Xim);
  kK<<<dim3(384,2), 256, 0, stream>>>(Xre, Xim, Vre, Vim, Kbp);
  kWb<<<1024, 256, 0, stream>>>(mk, W_feed, Wbt);

  // 2) embedding -> X0
  kEmbed<<<25600, 256, 0, stream>>>(mk, x, W_emb, b_emb, X0);

  // 3) three explicit S4D blocks, out-of-place ping-pong X0 <-> T2
  u16* cur = X0;
  u16* nxt = T2;
  for (int i=0;i<3;++i){
    kLN2<<<800,256,0,stream>>>(mk, cur, nullptr, ln_g, ln_b, i*H_, T1);
    kConvM<<<512, 512, CONV_LDS_BYTES, stream>>>(mk, T1, Kbp + i*H_*KROW_, Dp, i*H_, cur, nxt, 1, 0);
    u16* tmp = cur; cur = nxt; nxt = tmp;
  }
  u16* XINJ = cur;                         // T2
  u16* BT   = nxt;                         // X0: DEQ bounce buffer

  // 4) DEQ: z=0; 8 applications of f
  kZero<<<12800, 256, 0, stream>>>((uint4*)Zb, lossAcc);
  for (int it=0; it<8; ++it){
    int last = (it == 7);
    kLN2<<<800,256,0,stream>>>(mk, Zb, XINJ, ln_g, ln_b, 3*H_, T1);
    kConvM<<<512, 512, CONV_LDS_BYTES, stream>>>(mk, T1, Kbp + 3*H_*KROW_, Dp, 3*H_, nullptr, BT, 0, 0);
    kLN2<<<800,256,0,stream>>>(mk, BT, nullptr, ln_g, ln_b, 4*H_, T1);
    kConvM<<<512, 512, CONV_LDS_BYTES, stream>>>(mk, T1, Kbp + 4*H_*KROW_, Dp, 4*H_, nullptr, BT, 0, 0);
    kLN2<<<800,256,0,stream>>>(mk, BT, nullptr, ln_g, ln_b, 5*H_, T1);
    kConvM<<<512, 512, CONV_LDS_BYTES, stream>>>(mk, T1, Kbp + 5*H_*KROW_, Dp, 5*H_, nullptr, BT, 0, 1);
    kFF2<<<800, 512, FF2_LDS_BYTES, stream>>>(mk, BT, Wbt, b_feed, Zb, Zb, lossAcc, last);
  }

  // 5) outputs (X0/XINJ dead; d_out safe to finalize as f32)
  kMeanL<<<6400,256,0,stream>>>(Zb, Hbar);
  kScalars<<<1, 64, 0, stream>>>(lossAcc, outp);
  kTrans<<<dim3(16,8,50),256,0,stream>>>(Zb, outp + 501);
  kLogits<<<2,256,0,stream>>>(mk, Hbar, W_fc, b_fc, outp);
}

// Round 6
// 4207.944 us; speedup vs baseline: 1.1885x; 1.1885x over previous
//
#include <hip/hip_runtime.h>
#include <hip/hip_bf16.h>

typedef __hip_bfloat16 bf16;
typedef unsigned short u16;
typedef unsigned int u32;
typedef __attribute__((ext_vector_type(8))) short short8;
typedef __attribute__((ext_vector_type(4))) float f32x4;

#define B_ 50
#define L_ 1024
#define H_ 512
#define N_ 512
#define BL_ 51200        // B_*L_
#define HBL_ 26214400    // H_*BL_
#define KROW_ 1088       // L_ + 64 zero-pad front
#define PI_F 3.14159265358979323846f
#define MARK_BF16 0x3F803F80u
#define KRSW_ 1112       // u16 stride of one reversed-K copy
#define CONV_LDS_BYTES 151040  // (65536 + 8*1112 + 1088) u16 * 2

// kFF2 LDS layout (bytes): yt 65536 | res 9216 | bias 2048 | red 2048 = 78848
// (77 KB -> 2 blocks/CU; R5's 144 KB forced 1 block/CU = serial latency-bound)
#define FF_RES 65536
#define FF_SB  74752
#define FF_RED 76800
#define FF2_LDS_BYTES 78848
// swizzled byte addr within yt: 128B rows, XOR on 16B-slot bits
#define YTB(kc,n,cb) ((((kc)<<13) + ((n)<<7)) + ((cb) ^ (((((n)&7)^((n)>>3)^(kc))&7)<<4)))

__device__ __forceinline__ float u2f(u16 u){ union{u32 i; float f;} v; v.i = ((u32)u)<<16; return v.f; }
__device__ __forceinline__ u16  f2u(float x){ bf16 b = __float2bfloat16(x); return *(u16*)&b; }

__device__ __forceinline__ float ld_in(const void* p, int i, bool bff){
  if (bff){ u16 v = ((const u16*)p)[i]; union{u32 a; float f;} u; u.a = ((u32)v)<<16; return u.f; }
  return ((const float*)p)[i];
}

// fast tanh: 1 - 2/(e^{2|x|}+1), sign-restored. ~1e-6 abs err, way under bf16 quantum.
__device__ __forceinline__ float tanh_f(float x){
  float ax = fabsf(x);
  float e = __expf(2.f*ax);
  float r = 1.f - 2.f/(e + 1.f);
  return copysignf(r, x);
}

__device__ __forceinline__ float gelu_f(float x){
  float t = tanh_f(0.7978845608028654f*(x + 0.044715f*x*x*x));
  return 0.5f*x*(1.0f + t);
}

// ---------------- kernel synthesis ----------------
__global__ __launch_bounds__(256) void kV(float* __restrict__ Vre, float* __restrict__ Vim){
  int idx = blockIdx.x*256 + threadIdx.x;        // < N_*L_
  int n = idx >> 10, l = idx & 1023;
  int ph = (n*l) % 2000;                         // exact phase reduction
  float ang = (float)ph * (PI_F/1000.f);
  float mag = expf(-5e-4f*(float)l);
  float s, c;
  sincosf(ang, &s, &c);
  Vre[idx] = mag*c;
  Vim[idx] = mag*s;
}

__global__ __launch_bounds__(256) void kX(const u32* __restrict__ mk,
                                          const void* __restrict__ Cre, const void* __restrict__ Cim,
                                          float* __restrict__ Xre, float* __restrict__ Xim){
  const bool bff = (*mk == MARK_BF16);
  int idx = blockIdx.x*256 + threadIdx.x;        // < 6*H_*N_
  int n = idx & (N_-1);
  float ar = -0.5f, ai = PI_F*(float)n;
  float ex = expf(-5e-4f);
  float s, c;
  sincosf(1e-3f*ai, &s, &c);
  float dre = ex*c - 1.f;
  float dim = ex*s;
  float inv = 1.f/(ar*ar + ai*ai);
  float dBre = (dre*ar + dim*ai)*inv;
  float dBim = (dim*ar - dre*ai)*inv;
  float cr = ld_in(Cre, idx, bff), ci = ld_in(Cim, idx, bff);
  Xre[idx] = cr*dBre - ci*dBim;
  Xim[idx] = cr*dBim + ci*dBre;
}

// K -> bf16, padded. 8 rows x 2 cols/thread, 768 blocks (3/CU) for latency hiding.
__global__ __launch_bounds__(256) void kK(const float* __restrict__ Xre, const float* __restrict__ Xim,
                                          const float* __restrict__ Vre, const float* __restrict__ Vim,
                                          u16* __restrict__ Kbp){
  __shared__ float sxr[8*128], sxi[8*128];
  int kh0 = blockIdx.x*8;
  int l0 = blockIdx.y*512 + threadIdx.x;         // col A; col B = l0+256
  float accA[8], accB[8];
  #pragma unroll
  for (int t=0;t<8;++t){ accA[t]=0.f; accB[t]=0.f; }
  for (int nc=0; nc<4; ++nc){
    if (nc) __syncthreads();
    #pragma unroll
    for (int q=0;q<4;++q){
      int e = q*256 + threadIdx.x;               // < 1024
      int r = e >> 7, c = e & 127;
      sxr[e] = Xre[(kh0+r)*N_ + nc*128 + c];
      sxi[e] = Xim[(kh0+r)*N_ + nc*128 + c];
    }
    __syncthreads();
    for (int n4=0;n4<32;++n4){
      int nb = (nc*128 + n4*4)*L_ + l0;
      float vrA[4], viA[4], vrB[4], viB[4];
      #pragma unroll
      for (int k=0;k<4;++k){
        vrA[k] = Vre[nb + k*L_];       viA[k] = Vim[nb + k*L_];
        vrB[k] = Vre[nb + k*L_ + 256]; viB[k] = Vim[nb + k*L_ + 256];
      }
      #pragma unroll
      for (int t=0;t<8;++t){
        f32x4 xr = *(const f32x4*)&sxr[t*128 + n4*4];
        f32x4 xi = *(const f32x4*)&sxi[t*128 + n4*4];
        float a = accA[t], b = accB[t];
        #pragma unroll
        for (int k=0;k<4;++k){
          a += xr[k]*vrA[k] - xi[k]*viA[k];
          b += xr[k]*vrB[k] - xi[k]*viB[k];
        }
        accA[t] = a; accB[t] = b;
      }
    }
  }
  #pragma unroll
  for (int t=0;t<8;++t){
    Kbp[(kh0+t)*KROW_ + 64 + l0]       = f2u(2.f*accA[t]);
    Kbp[(kh0+t)*KROW_ + 64 + l0 + 256] = f2u(2.f*accB[t]);
  }
  if (blockIdx.y == 0 && threadIdx.x < 64){
    #pragma unroll
    for (int t=0;t<8;++t) Kbp[(kh0+t)*KROW_ + threadIdx.x] = 0;
  }
}

// W_feed [k][m] f32 -> Wbt [m][k] bf16
__global__ __launch_bounds__(256) void kWb(const u32* __restrict__ mk,
                                           const void* __restrict__ W, u16* __restrict__ Wbt){
  const bool bff = (*mk == MARK_BF16);
  int idx = blockIdx.x*256 + threadIdx.x;        // < 262144
  int k = idx >> 9, m = idx & 511;
  Wbt[m*512 + k] = f2u(ld_in(W, k*512 + m, bff));
}

// ---------------- embedding ----------------
__global__ __launch_bounds__(256) void kEmbed(const u32* __restrict__ mk,
                                              const void* __restrict__ x, const void* __restrict__ W,
                                              const void* __restrict__ be, u16* __restrict__ out){
  const bool bff = (*mk == MARK_BF16);
  int t = blockIdx.x*256 + threadIdx.x;          // < HBL_/4
  int e = t*4;
  int h = e / BL_;
  int col = e - h*BL_;
  float w = ld_in(W, h, bff), bb = ld_in(be, h, bff);
  ushort4 o;
  o.x = f2u(ld_in(x, col+0, bff)*w + bb);
  o.y = f2u(ld_in(x, col+1, bff)*w + bb);
  o.z = f2u(ld_in(x, col+2, bff)*w + bb);
  o.w = f2u(ld_in(x, col+3, bff)*w + bb);
  *(ushort4*)(out + e) = o;
}

// ---------------- zero Z + loss accumulator ----------------
__global__ __launch_bounds__(256) void kZero(uint4* __restrict__ Z, float* __restrict__ lossAcc){
  int t = blockIdx.x*256 + threadIdx.x;          // < HBL_*2/16
  Z[t] = make_uint4(0u,0u,0u,0u);
  if (t == 0) *lossAcc = 0.f;
}

// ---------------- LayerNorm over h; vectorized uint4 loads, col-octet/thread ----------------
__global__ __launch_bounds__(256) void kLN2(const u32* __restrict__ mk,
                                            const u16* __restrict__ U, const u16* __restrict__ U2,
                                            const void* __restrict__ g, const void* __restrict__ bb,
                                            int off, u16* __restrict__ Vout){
  const bool bff = (*mk == MARK_BF16);
  __shared__ float rs[32][64], rq[32][64], ms[64], rr[64], gs[512], bs[512];
  int c8 = threadIdx.x & 7;                      // col-octet within 64-col tile
  int ty = threadIdx.x >> 3;                     // 0..31
  int colb = blockIdx.x*64 + c8*8;
  // stage g/b
  for (int i = threadIdx.x; i < 512; i += 256){
    gs[i] = ld_in(g, off+i, bff);
    bs[i] = ld_in(bb, off+i, bff);
  }
  float s8[8], q8[8];
  #pragma unroll
  for (int j=0;j<8;++j){ s8[j]=0.f; q8[j]=0.f; }
  for (int p=0;p<16;++p){
    int h = ty + p*32;
    uint4 uv = *(const uint4*)(U + (size_t)h*BL_ + colb);
    const u16* pu = (const u16*)&uv;
    float xv[8];
    #pragma unroll
    for (int j=0;j<8;++j) xv[j] = u2f(pu[j]);
    if (U2){
      uint4 uv2 = *(const uint4*)(U2 + (size_t)h*BL_ + colb);
      const u16* p2 = (const u16*)&uv2;
      #pragma unroll
      for (int j=0;j<8;++j) xv[j] += u2f(p2[j]);
    }
    #pragma unroll
    for (int j=0;j<8;++j){ s8[j] += xv[j]; q8[j] += xv[j]*xv[j]; }
  }
  *(f32x4*)&rs[ty][c8*8]   = (f32x4){s8[0],s8[1],s8[2],s8[3]};
  *(f32x4*)&rs[ty][c8*8+4] = (f32x4){s8[4],s8[5],s8[6],s8[7]};
  *(f32x4*)&rq[ty][c8*8]   = (f32x4){q8[0],q8[1],q8[2],q8[3]};
  *(f32x4*)&rq[ty][c8*8+4] = (f32x4){q8[4],q8[5],q8[6],q8[7]};
  __syncthreads();
  if (threadIdx.x < 64){
    int c = threadIdx.x;
    float st = 0.f, qt = 0.f;
    #pragma unroll 8
    for (int t2=0;t2<32;++t2){ st += rs[t2][c]; qt += rq[t2][c]; }
    float mean = st*(1.f/512.f);
    float var  = qt*(1.f/512.f) - mean*mean;
    ms[c] = mean;
    rr[c] = rsqrtf(var + 1e-5f);
  }
  __syncthreads();
  float mean8[8], rstd8[8];
  #pragma unroll
  for (int j=0;j<8;++j){ mean8[j] = ms[c8*8+j]; rstd8[j] = rr[c8*8+j]; }
  for (int p=0;p<16;++p){
    int h = ty + p*32;
    uint4 uv = *(const uint4*)(U + (size_t)h*BL_ + colb);
    const u16* pu = (const u16*)&uv;
    float xv[8];
    #pragma unroll
    for (int j=0;j<8;++j) xv[j] = u2f(pu[j]);
    if (U2){
      uint4 uv2 = *(const uint4*)(U2 + (size_t)h*BL_ + colb);
      const u16* p2 = (const u16*)&uv2;
      #pragma unroll
      for (int j=0;j<8;++j) xv[j] += u2f(p2[j]);
    }
    float gv = gs[h], bv = bs[h];
    union { uint4 v; u16 s[8]; } ob;
    #pragma unroll
    for (int j=0;j<8;++j) ob.s[j] = f2u((xv[j]-mean8[j])*rstd8[j]*gv + bv);
    *(uint4*)(Vout + (size_t)h*BL_ + colb) = ob.v;
  }
}

// ---------------- MFMA causal conv, one block per h ----------------
__global__ __launch_bounds__(512, 2) void kConvM(const u32* __restrict__ mk,
                                              const u16* __restrict__ V, const u16* __restrict__ Kb,
                                              const void* __restrict__ Dv, int dOff,
                                              const u16* __restrict__ U,
                                              u16* __restrict__ Y, int skip, int doGelu){
  extern __shared__ u16 lds[];
  u16* sV  = lds;                    // 64 rows x 1024 u16, swizzled (131072 B)
  u16* sKR = lds + 65536;            // 8 copies x KRSW_ (17792 B)
  u16* sKt = lds + 65536 + 8*KRSW_;  // Kpad row tmp (2176 B)
  const bool bff = (*mk == MARK_BF16);
  int h = blockIdx.x;
  int tid = threadIdx.x;
  const u16* Kbh = Kb + h*KROW_;
  for (int s = tid; s < 1088; s += 512) sKt[s] = Kbh[s];
  __syncthreads();
  #pragma unroll
  for (int p = 0; p < 8; ++p){
    for (int s = tid; s < KRSW_; s += 512){
      int idx = 1087 - s - p;
      sKR[p*KRSW_ + s] = (idx >= 0) ? sKt[idx] : (u16)0;
    }
  }
  {
    const u16* Vh = V + (size_t)h*(B_*L_);
    #pragma unroll
    for (int q = 0; q < 16; ++q){
      int chunk = q*512 + tid;        // 0..8191 16B-chunks
      int r = chunk >> 7;
      int c16 = chunk & 127;
      uint4 dval = *(const uint4*)(Vh + r*L_ + c16*8);
      u32 byte = ((u32)r << 11) + ((u32)c16 << 4);
      byte ^= ((u32)(r & 7) << 4);
      *(uint4*)((char*)sV + byte) = dval;
    }
  }
  __syncthreads();
  int wv = tid >> 6, lane = tid & 63;
  int nl = lane & 15, quad = lane >> 4;
  float Dh = ld_in(Dv, dOff + h, bff);
  #pragma unroll 1
  for (int cc = 0; cc < 2; ++cc){
    int c_out = cc ? (15 - wv) : wv;
    f32x4 acc[4][4];
    #pragma unroll
    for (int mt=0;mt<4;++mt){
      #pragma unroll
      for (int nt=0;nt<4;++nt) acc[mt][nt] = (f32x4){0.f,0.f,0.f,0.f};
    }
    for (int ci = 0; ci <= c_out; ++ci){
      int d = c_out - ci;
      short8 a0[4], a1[4], b0[4], b1[4];
      #pragma unroll
      for (int mt=0;mt<4;++mt){
        int r = mt*16 + nl;
        u32 msk = (u32)(r & 7) << 4;
        u32 base = ((u32)r << 11) + (u32)((ci*64 + quad*8) << 1);
        a0[mt] = *(const short8*)((const char*)sV + (base ^ msk));
        a1[mt] = *(const short8*)((const char*)sV + ((base + 64u) ^ msk));
      }
      #pragma unroll
      for (int nt=0;nt<4;++nt){
        int i = nt*16 + nl;
        int t0 = 1023 - d*64 - i + quad*8;     // in [0,1054]
        const u16* bp = sKR + (t0 & 7)*KRSW_ + (t0 & ~7);
        b0[nt] = *(const short8*)bp;
        b1[nt] = *(const short8*)(bp + 32);
      }
      #pragma unroll
      for (int mt=0;mt<4;++mt){
        #pragma unroll
        for (int nt=0;nt<4;++nt){
          acc[mt][nt] = __builtin_amdgcn_mfma_f32_16x16x32_bf16(a0[mt], b0[nt], acc[mt][nt], 0,0,0);
          acc[mt][nt] = __builtin_amdgcn_mfma_f32_16x16x32_bf16(a1[mt], b1[nt], acc[mt][nt], 0,0,0);
        }
      }
    }
    #pragma unroll
    for (int mt=0;mt<4;++mt){
      #pragma unroll
      for (int reg=0;reg<4;++reg){
        int b = mt*16 + quad*4 + reg;
        if (b < B_){
          #pragma unroll
          for (int nt=0;nt<4;++nt){
            int col = c_out*64 + nt*16 + nl;
            u32 vb = (((u32)b << 11) + ((u32)col << 1)) ^ ((u32)(b & 7) << 4);
            float vv = u2f(*(const u16*)((const char*)sV + vb));
            size_t gi = (size_t)(h*B_ + b)*L_ + col;
            float y = tanh_f(acc[mt][nt][reg] + vv*Dh);
            if (skip) y += u2f(U[gi]);
            if (doGelu) y = gelu_f(y);
            Y[gi] = f2u(y);
          }
        }
      }
    }
  }
}

// ---------------- MFMA FF v4: per block = 64-n stripe x ALL 512 m ----------------
// Z[m,n] = gelu(sum_k W_feed[k,m]*Y[k,n] + bias[m]).
// Y tile transposed ONCE into swizzled LDS (64 KB). A-fragments read DIRECTLY
// from Wbt in L2 (0.5 MB, resident; same bytes the old wa-staging delivered, so
// accumulation is bitwise identical). LDS 144 KB -> 77 KB = 2 blocks/CU, which
// is the point: R5 ran 1 block/CU with every pipe <25% busy (latency-bound).
// Results staged in res, flushed as full-128B-line uint4 stores.
__global__ __launch_bounds__(512, 4) void kFF2(const u32* __restrict__ mk,
                                            const u16* __restrict__ Yin, const u16* __restrict__ Wbt,
                                            const void* __restrict__ bias, u16* __restrict__ Zout,
                                            const u16* __restrict__ Zold, float* __restrict__ lossAcc,
                                            int doLoss){
  extern __shared__ char ldsF[];
  u16* res  = (u16*)(ldsF + FF_RES);      // [64][72] u16
  float* sb = (float*)(ldsF + FF_SB);     // bias[512]
  float* red= (float*)(ldsF + FF_RED);    // loss reduction[512]
  const bool bff = (*mk == MARK_BF16);
  int n0g = blockIdx.x*64;
  int tid = threadIdx.x;

  sb[tid & 511] = ld_in(bias, tid & 511, bff);

  // transpose Y (64 n x 512 k) into yt, swizzled
  {
    int rY = tid >> 3, q3 = tid & 7;
    #pragma unroll
    for (int kc=0;kc<8;++kc){
      const u16* yp = Yin + (size_t)(kc*64 + rY)*BL_ + n0g + q3*8;
      uint4 v = *(const uint4*)yp;
      const u16* pv = (const u16*)&v;
      int nb = q3*8;
      #pragma unroll
      for (int j=0;j<8;++j) *(u16*)(ldsF + YTB(kc, nb+j, rY*2)) = pv[j];
    }
  }
  __syncthreads();

  int wv = tid >> 6, lane = tid & 63;
  int nl = lane & 15, quad = lane >> 4;
  int mt = wv >> 1, ntb = (wv & 1)*2;
  int mrow = mt*16 + nl;
  int nr0 = ntb*16 + nl, nr1 = nr0 + 16;

  float ls = 0.f;
  int frow = tid >> 3, fcol = (tid & 7)*8;

  #pragma unroll 1
  for (int mc=0; mc<8; ++mc){
    f32x4 acc0 = (f32x4){0.f,0.f,0.f,0.f};
    f32x4 acc1 = (f32x4){0.f,0.f,0.f,0.f};
    const u16* wrow = Wbt + (size_t)(mc*64 + mrow)*512 + quad*8;
    #pragma unroll
    for (int kc=0;kc<8;++kc){
      short8 a0  = *(const short8*)(wrow + kc*64);          // L2-resident W
      short8 a1  = *(const short8*)(wrow + kc*64 + 32);
      short8 b00 = *(const short8*)(ldsF + YTB(kc, nr0, quad*16));
      short8 b01 = *(const short8*)(ldsF + YTB(kc, nr0, 64 + quad*16));
      short8 b10 = *(const short8*)(ldsF + YTB(kc, nr1, quad*16));
      short8 b11 = *(const short8*)(ldsF + YTB(kc, nr1, 64 + quad*16));
      acc0 = __builtin_amdgcn_mfma_f32_16x16x32_bf16(a0, b00, acc0, 0,0,0);
      acc0 = __builtin_amdgcn_mfma_f32_16x16x32_bf16(a1, b01, acc0, 0,0,0);
      acc1 = __builtin_amdgcn_mfma_f32_16x16x32_bf16(a0, b10, acc1, 0,0,0);
      acc1 = __builtin_amdgcn_mfma_f32_16x16x32_bf16(a1, b11, acc1, 0,0,0);
    }
    // epilogue -> res (per-wave disjoint regions)
    #pragma unroll
    for (int reg=0;reg<4;++reg){
      int mloc = mt*16 + quad*4 + reg;
      float bv = sb[mc*64 + mloc];
      res[mloc*72 + ntb*16 + nl]      = f2u(gelu_f(acc0[reg] + bv));
      res[mloc*72 + ntb*16 + nl + 16] = f2u(gelu_f(acc1[reg] + bv));
    }
    __syncthreads();   // res complete
    // flush: one full 128B line per 8-lane group
    {
      size_t zoff = (size_t)(mc*64 + frow)*BL_ + n0g + fcol;
      uint4 v = *(const uint4*)&res[frow*72 + fcol];
      if (doLoss){
        uint4 zo = *(const uint4*)(Zold + zoff);
        const u16* pv = (const u16*)&v;
        const u16* po = (const u16*)&zo;
        #pragma unroll
        for (int j=0;j<8;++j){ float d = u2f(pv[j]) - u2f(po[j]); ls += d*d; }
      }
      *(uint4*)(Zout + zoff) = v;
    }
    __syncthreads();   // res free for next epilogue
  }
  if (doLoss){
    red[tid] = ls;
    __syncthreads();
    for (int off=256; off>0; off>>=1){
      if (tid < off) red[tid] += red[tid+off];
      __syncthreads();
    }
    if (tid==0) atomicAdd(lossAcc, red[0]);
  }
}

// ---------------- scalars: loss + n_deq (f32 out) ----------------
__global__ void kScalars(const float* __restrict__ lossAcc, float* __restrict__ outp){
  if (threadIdx.x == 0 && blockIdx.x == 0){
    outp[500] = *lossAcc * (1.f/26214400.f);
    outp[26214901] = 8.0f;
  }
}

// ---------------- transpose [H,B,L] bf16 -> out[b,l,h] f32 ----------------
__global__ __launch_bounds__(256) void kTrans(const u16* __restrict__ Z, float* __restrict__ out){
  __shared__ u16 st[64][68];
  int b = blockIdx.z, h0 = blockIdx.y*64, l0 = blockIdx.x*64;
  int tid = threadIdx.x;
  int r = tid >> 2, q = tid & 3;
  const u16* src = Z + ((h0+r)*B_ + b)*L_ + l0 + q*16;
  #pragma unroll
  for (int c=0; c<4; ++c){
    ushort4 v = *(const ushort4*)(src + c*4);
    st[r][q*16 + c*4 + 0] = v.x;
    st[r][q*16 + c*4 + 1] = v.y;
    st[r][q*16 + c*4 + 2] = v.z;
    st[r][q*16 + c*4 + 3] = v.w;
  }
  __syncthreads();
  int i = tid & 63;
  int j0 = tid >> 6;
  for (int jj = j0; jj < 64; jj += 4){
    out[(size_t)(b*L_ + l0 + jj)*H_ + h0 + i] = u2f(st[i][jj]);
  }
}

// ---------------- mean over l ----------------
__global__ __launch_bounds__(256) void kMeanL(const u16* __restrict__ Z, float* __restrict__ Hb){
  int lane = threadIdx.x & 63;
  int ridx = blockIdx.x*4 + (threadIdx.x >> 6);  // = ho*B_+b
  const u16* row = Z + (size_t)ridx*L_;
  float s = 0.f;
  for (int ii=lane; ii<L_; ii+=64) s += u2f(row[ii]);
  for (int off=32; off>0; off>>=1) s += __shfl_down(s, off, 64);
  if (lane==0){
    int ho = ridx / B_, b = ridx - ho*B_;
    Hb[b*H_ + ho] = s*(1.f/1024.f);
  }
}

__global__ __launch_bounds__(256) void kLogits(const u32* __restrict__ mk,
                                               const float* __restrict__ Hb, const void* __restrict__ Wfc,
                                               const void* __restrict__ bfc, float* __restrict__ outp){
  const bool bff = (*mk == MARK_BF16);
  int t = blockIdx.x*256 + threadIdx.x;
  if (t < 500){
    int b = t/10, c = t - (t/10)*10;
    float s = ld_in(bfc, c, bff);
    for (int ho=0; ho<H_; ++ho) s += Hb[b*H_+ho]*ld_in(Wfc, ho*10+c, bff);
    outp[t] = s;
  }
}

extern "C" void kernel_launch(void* const* d_in, const int* in_sizes, int n_in,
                              void* d_out, int out_size, void* d_ws, size_t ws_size,
                              hipStream_t stream) {
  (void)in_sizes; (void)n_in; (void)out_size; (void)ws_size;
  const void* x      = d_in[0];
  const void* W_emb  = d_in[1];
  const void* b_emb  = d_in[2];
  const void* C_re   = d_in[3];
  const void* C_im   = d_in[4];
  const void* Dp     = d_in[5];
  const void* ln_g   = d_in[6];
  const void* ln_b   = d_in[7];
  const void* W_feed = d_in[8];
  const void* b_feed = d_in[9];
  const void* W_fc   = d_in[10];
  const void* b_fc   = d_in[11];
  const u32* mk = (const u32*)d_in[5];
  float* outp = (float*)d_out;

  static int s_attr = 0;
  if (!s_attr){
    hipFuncSetAttribute(reinterpret_cast<const void*>(kConvM),
                        hipFuncAttributeMaxDynamicSharedMemorySize, CONV_LDS_BYTES);
    hipFuncSetAttribute(reinterpret_cast<const void*>(kFF2),
                        hipFuncAttributeMaxDynamicSharedMemorySize, FF2_LDS_BYTES);
    s_attr = 1;
  }

  // ws: Kbp bf16[6*512*1088] | Zb | T1 | T2 (bf16 HBL each) | Hbar f32 | lossAcc | Wbt (~164.6 MB)
  u16* Kbp = (u16*)d_ws;
  u16* Zb  = Kbp + 6*H_*KROW_;
  u16* T1  = Zb + HBL_;
  u16* T2  = T1 + HBL_;
  float* Hbar = (float*)(T2 + HBL_);
  float* lossAcc = Hbar + 25600;
  u16* Wbt = (u16*)(Hbar + 25604);               // 0.5 MB, 16B-aligned
  // d_out-resident scratch: X0 (bf16 HBL, bytes 0..52.4MB); dead before final writes.
  u16* X0  = (u16*)d_out;
  // phase-A f32 scratch carved from T1
  float* Vre = (float*)T1;
  float* Vim = Vre + N_*L_;
  float* Xre = Vim + N_*L_;
  float* Xim = Xre + 6*H_*N_;

  // 1) kernels K (bf16 padded) + W transpose
  kV<<<2048, 256, 0, stream>>>(Vre, Vim);
  kX<<<6144, 256, 0, stream>>>(mk, C_re, C_im, Xre, Xim);
  kK<<<dim3(384,2), 256, 0, stream>>>(Xre, Xim, Vre, Vim, Kbp);
  kWb<<<1024, 256, 0, stream>>>(mk, W_feed, Wbt);

  // 2) embedding -> X0
  kEmbed<<<25600, 256, 0, stream>>>(mk, x, W_emb, b_emb, X0);

  // 3) three explicit S4D blocks, out-of-place ping-pong X0 <-> T2
  u16* cur = X0;
  u16* nxt = T2;
  for (int i=0;i<3;++i){
    kLN2<<<800,256,0,stream>>>(mk, cur, nullptr, ln_g, ln_b, i*H_, T1);
    kConvM<<<512, 512, CONV_LDS_BYTES, stream>>>(mk, T1, Kbp + i*H_*KROW_, Dp, i*H_, cur, nxt, 1, 0);
    u16* tmp = cur; cur = nxt; nxt = tmp;
  }
  u16* XINJ = cur;                         // T2
  u16* BT   = nxt;                         // X0: DEQ bounce buffer

  // 4) DEQ: z=0; 8 applications of f
  kZero<<<12800, 256, 0, stream>>>((uint4*)Zb, lossAcc);
  for (int it=0; it<8; ++it){
    int last = (it == 7);
    kLN2<<<800,256,0,stream>>>(mk, Zb, XINJ, ln_g, ln_b, 3*H_, T1);
    kConvM<<<512, 512, CONV_LDS_BYTES, stream>>>(mk, T1, Kbp + 3*H_*KROW_, Dp, 3*H_, nullptr, BT, 0, 0);
    kLN2<<<800,256,0,stream>>>(mk, BT, nullptr, ln_g, ln_b, 4*H_, T1);
    kConvM<<<512, 512, CONV_LDS_BYTES, stream>>>(mk, T1, Kbp + 4*H_*KROW_, Dp, 4*H_, nullptr, BT, 0, 0);
    kLN2<<<800,256,0,stream>>>(mk, BT, nullptr, ln_g, ln_b, 5*H_, T1);
    kConvM<<<512, 512, CONV_LDS_BYTES, stream>>>(mk, T1, Kbp + 5*H_*KROW_, Dp, 5*H_, nullptr, BT, 0, 1);
    kFF2<<<800, 512, FF2_LDS_BYTES, stream>>>(mk, BT, Wbt, b_feed, Zb, Zb, lossAcc, last);
  }

  // 5) outputs (X0/XINJ dead; d_out safe to finalize as f32)
  kMeanL<<<6400,256,0,stream>>>(Zb, Hbar);
  kScalars<<<1, 64, 0, stream>>>(lossAcc, outp);
  kTrans<<<dim3(16,8,50),256,0,stream>>>(Zb, outp + 501);
  kLogits<<<2,256,0,stream>>>(mk, Hbar, W_fc, b_fc, outp);
}

// Round 7
// 4058.937 us; speedup vs baseline: 1.2321x; 1.0367x over previous
//
#include <hip/hip_runtime.h>
#include <hip/hip_bf16.h>

typedef __hip_bfloat16 bf16;
typedef unsigned short u16;
typedef unsigned int u32;
typedef __attribute__((ext_vector_type(8))) short short8;
typedef __attribute__((ext_vector_type(4))) float f32x4;

#define B_ 50
#define L_ 1024
#define H_ 512
#define N_ 512
#define BL_ 51200        // B_*L_
#define HBL_ 26214400    // H_*BL_
#define KROW_ 1088       // L_ + 64 zero-pad front
#define PI_F 3.14159265358979323846f
#define MARK_BF16 0x3F803F80u
#define KRSW_ 1112       // u16 stride of one reversed-K copy
#define CONV_LDS_BYTES 151040  // (65536 + 8*1112 + 1088) u16 * 2

// kFF2 LDS layout (bytes): yt 65536 | res 9216 | bias 2048 | red 2048 = 78848
#define FF_RES 65536
#define FF_SB  74752
#define FF_RED 76800
#define FF2_LDS_BYTES 78848
// swizzled byte addr within yt: 128B rows, XOR on 16B-slot bits
#define YTB(kc,n,cb) ((((kc)<<13) + ((n)<<7)) + ((cb) ^ (((((n)&7)^((n)>>3)^(kc))&7)<<4)))

__device__ __forceinline__ float u2f(u16 u){ union{u32 i; float f;} v; v.i = ((u32)u)<<16; return v.f; }
__device__ __forceinline__ u16  f2u(float x){ bf16 b = __float2bfloat16(x); return *(u16*)&b; }

__device__ __forceinline__ float ld_in(const void* p, int i, bool bff){
  if (bff){ u16 v = ((const u16*)p)[i]; union{u32 a; float f;} u; u.a = ((u32)v)<<16; return u.f; }
  return ((const float*)p)[i];
}

// fast tanh: 1 - 2/(e^{2|x|}+1), sign-restored. ~1e-6 abs err, way under bf16 quantum.
__device__ __forceinline__ float tanh_f(float x){
  float ax = fabsf(x);
  float e = __expf(2.f*ax);
  float r = 1.f - 2.f/(e + 1.f);
  return copysignf(r, x);
}

__device__ __forceinline__ float gelu_f(float x){
  float t = tanh_f(0.7978845608028654f*(x + 0.044715f*x*x*x));
  return 0.5f*x*(1.0f + t);
}

// ---------------- kernel synthesis ----------------
__global__ __launch_bounds__(256) void kV(float* __restrict__ Vre, float* __restrict__ Vim){
  int idx = blockIdx.x*256 + threadIdx.x;        // < N_*L_
  int n = idx >> 10, l = idx & 1023;
  int ph = (n*l) % 2000;                         // exact phase reduction
  float ang = (float)ph * (PI_F/1000.f);
  float mag = expf(-5e-4f*(float)l);
  float s, c;
  sincosf(ang, &s, &c);
  Vre[idx] = mag*c;
  Vim[idx] = mag*s;
}

__global__ __launch_bounds__(256) void kX(const u32* __restrict__ mk,
                                          const void* __restrict__ Cre, const void* __restrict__ Cim,
                                          float* __restrict__ Xre, float* __restrict__ Xim){
  const bool bff = (*mk == MARK_BF16);
  int idx = blockIdx.x*256 + threadIdx.x;        // < 6*H_*N_
  int n = idx & (N_-1);
  float ar = -0.5f, ai = PI_F*(float)n;
  float ex = expf(-5e-4f);
  float s, c;
  sincosf(1e-3f*ai, &s, &c);
  float dre = ex*c - 1.f;
  float dim = ex*s;
  float inv = 1.f/(ar*ar + ai*ai);
  float dBre = (dre*ar + dim*ai)*inv;
  float dBim = (dim*ar - dre*ai)*inv;
  float cr = ld_in(Cre, idx, bff), ci = ld_in(Cim, idx, bff);
  Xre[idx] = cr*dBre - ci*dBim;
  Xim[idx] = cr*dBim + ci*dBre;
}

// K -> bf16, padded. 8 rows x 2 cols/thread, 768 blocks (3/CU) for latency hiding.
__global__ __launch_bounds__(256) void kK(const float* __restrict__ Xre, const float* __restrict__ Xim,
                                          const float* __restrict__ Vre, const float* __restrict__ Vim,
                                          u16* __restrict__ Kbp){
  __shared__ float sxr[8*128], sxi[8*128];
  int kh0 = blockIdx.x*8;
  int l0 = blockIdx.y*512 + threadIdx.x;         // col A; col B = l0+256
  float accA[8], accB[8];
  #pragma unroll
  for (int t=0;t<8;++t){ accA[t]=0.f; accB[t]=0.f; }
  for (int nc=0; nc<4; ++nc){
    if (nc) __syncthreads();
    #pragma unroll
    for (int q=0;q<4;++q){
      int e = q*256 + threadIdx.x;               // < 1024
      int r = e >> 7, c = e & 127;
      sxr[e] = Xre[(kh0+r)*N_ + nc*128 + c];
      sxi[e] = Xim[(kh0+r)*N_ + nc*128 + c];
    }
    __syncthreads();
    for (int n4=0;n4<32;++n4){
      int nb = (nc*128 + n4*4)*L_ + l0;
      float vrA[4], viA[4], vrB[4], viB[4];
      #pragma unroll
      for (int k=0;k<4;++k){
        vrA[k] = Vre[nb + k*L_];       viA[k] = Vim[nb + k*L_];
        vrB[k] = Vre[nb + k*L_ + 256]; viB[k] = Vim[nb + k*L_ + 256];
      }
      #pragma unroll
      for (int t=0;t<8;++t){
        f32x4 xr = *(const f32x4*)&sxr[t*128 + n4*4];
        f32x4 xi = *(const f32x4*)&sxi[t*128 + n4*4];
        float a = accA[t], b = accB[t];
        #pragma unroll
        for (int k=0;k<4;++k){
          a += xr[k]*vrA[k] - xi[k]*viA[k];
          b += xr[k]*vrB[k] - xi[k]*viB[k];
        }
        accA[t] = a; accB[t] = b;
      }
    }
  }
  #pragma unroll
  for (int t=0;t<8;++t){
    Kbp[(kh0+t)*KROW_ + 64 + l0]       = f2u(2.f*accA[t]);
    Kbp[(kh0+t)*KROW_ + 64 + l0 + 256] = f2u(2.f*accB[t]);
  }
  if (blockIdx.y == 0 && threadIdx.x < 64){
    #pragma unroll
    for (int t=0;t<8;++t) Kbp[(kh0+t)*KROW_ + threadIdx.x] = 0;
  }
}

// W_feed [k][m] f32 -> Wbt [m][k] bf16
__global__ __launch_bounds__(256) void kWb(const u32* __restrict__ mk,
                                           const void* __restrict__ W, u16* __restrict__ Wbt){
  const bool bff = (*mk == MARK_BF16);
  int idx = blockIdx.x*256 + threadIdx.x;        // < 262144
  int k = idx >> 9, m = idx & 511;
  Wbt[m*512 + k] = f2u(ld_in(W, k*512 + m, bff));
}

// ---------------- embedding ----------------
__global__ __launch_bounds__(256) void kEmbed(const u32* __restrict__ mk,
                                              const void* __restrict__ x, const void* __restrict__ W,
                                              const void* __restrict__ be, u16* __restrict__ out){
  const bool bff = (*mk == MARK_BF16);
  int t = blockIdx.x*256 + threadIdx.x;          // < HBL_/4
  int e = t*4;
  int h = e / BL_;
  int col = e - h*BL_;
  float w = ld_in(W, h, bff), bb = ld_in(be, h, bff);
  ushort4 o;
  o.x = f2u(ld_in(x, col+0, bff)*w + bb);
  o.y = f2u(ld_in(x, col+1, bff)*w + bb);
  o.z = f2u(ld_in(x, col+2, bff)*w + bb);
  o.w = f2u(ld_in(x, col+3, bff)*w + bb);
  *(ushort4*)(out + e) = o;
}

// ---------------- zero Z + loss accumulator ----------------
__global__ __launch_bounds__(256) void kZero(uint4* __restrict__ Z, float* __restrict__ lossAcc){
  int t = blockIdx.x*256 + threadIdx.x;          // < HBL_*2/16
  Z[t] = make_uint4(0u,0u,0u,0u);
  if (t == 0) *lossAcc = 0.f;
}

// ---------------- LayerNorm over h; vectorized uint4 loads, col-octet/thread ----------------
__global__ __launch_bounds__(256) void kLN2(const u32* __restrict__ mk,
                                            const u16* __restrict__ U, const u16* __restrict__ U2,
                                            const void* __restrict__ g, const void* __restrict__ bb,
                                            int off, u16* __restrict__ Vout){
  const bool bff = (*mk == MARK_BF16);
  __shared__ float rs[32][64], rq[32][64], ms[64], rr[64], gs[512], bs[512];
  int c8 = threadIdx.x & 7;                      // col-octet within 64-col tile
  int ty = threadIdx.x >> 3;                     // 0..31
  int colb = blockIdx.x*64 + c8*8;
  // stage g/b
  for (int i = threadIdx.x; i < 512; i += 256){
    gs[i] = ld_in(g, off+i, bff);
    bs[i] = ld_in(bb, off+i, bff);
  }
  float s8[8], q8[8];
  #pragma unroll
  for (int j=0;j<8;++j){ s8[j]=0.f; q8[j]=0.f; }
  for (int p=0;p<16;++p){
    int h = ty + p*32;
    uint4 uv = *(const uint4*)(U + (size_t)h*BL_ + colb);
    const u16* pu = (const u16*)&uv;
    float xv[8];
    #pragma unroll
    for (int j=0;j<8;++j) xv[j] = u2f(pu[j]);
    if (U2){
      uint4 uv2 = *(const uint4*)(U2 + (size_t)h*BL_ + colb);
      const u16* p2 = (const u16*)&uv2;
      #pragma unroll
      for (int j=0;j<8;++j) xv[j] += u2f(p2[j]);
    }
    #pragma unroll
    for (int j=0;j<8;++j){ s8[j] += xv[j]; q8[j] += xv[j]*xv[j]; }
  }
  *(f32x4*)&rs[ty][c8*8]   = (f32x4){s8[0],s8[1],s8[2],s8[3]};
  *(f32x4*)&rs[ty][c8*8+4] = (f32x4){s8[4],s8[5],s8[6],s8[7]};
  *(f32x4*)&rq[ty][c8*8]   = (f32x4){q8[0],q8[1],q8[2],q8[3]};
  *(f32x4*)&rq[ty][c8*8+4] = (f32x4){q8[4],q8[5],q8[6],q8[7]};
  __syncthreads();
  if (threadIdx.x < 64){
    int c = threadIdx.x;
    float st = 0.f, qt = 0.f;
    #pragma unroll 8
    for (int t2=0;t2<32;++t2){ st += rs[t2][c]; qt += rq[t2][c]; }
    float mean = st*(1.f/512.f);
    float var  = qt*(1.f/512.f) - mean*mean;
    ms[c] = mean;
    rr[c] = rsqrtf(var + 1e-5f);
  }
  __syncthreads();
  float mean8[8], rstd8[8];
  #pragma unroll
  for (int j=0;j<8;++j){ mean8[j] = ms[c8*8+j]; rstd8[j] = rr[c8*8+j]; }
  for (int p=0;p<16;++p){
    int h = ty + p*32;
    uint4 uv = *(const uint4*)(U + (size_t)h*BL_ + colb);
    const u16* pu = (const u16*)&uv;
    float xv[8];
    #pragma unroll
    for (int j=0;j<8;++j) xv[j] = u2f(pu[j]);
    if (U2){
      uint4 uv2 = *(const uint4*)(U2 + (size_t)h*BL_ + colb);
      const u16* p2 = (const u16*)&uv2;
      #pragma unroll
      for (int j=0;j<8;++j) xv[j] += u2f(p2[j]);
    }
    float gv = gs[h], bv = bs[h];
    union { uint4 v; u16 s[8]; } ob;
    #pragma unroll
    for (int j=0;j<8;++j) ob.s[j] = f2u((xv[j]-mean8[j])*rstd8[j]*gv + bv);
    *(uint4*)(Vout + (size_t)h*BL_ + colb) = ob.v;
  }
}

// ---------------- MFMA causal conv v2: one block per h, 16 waves, 1 c_out/wave ----
// R6 ran 8 waves (2/SIMD): ds_read->MFMA latency exposed. 16 waves = 4/SIMD hides
// it; early-finishing waves (small c_out) run their epilogue under wave-15's tail.
// Per-output accumulation order identical to v1 (ci ascending, a0b0 then a1b1).
// VGPR discipline: acc 64 + B-frags 32 + A 8 + addr ~ 115 <= 128 cap of 1024-thr.
__global__ __launch_bounds__(1024) void kConvM(const u32* __restrict__ mk,
                                              const u16* __restrict__ V, const u16* __restrict__ Kb,
                                              const void* __restrict__ Dv, int dOff,
                                              const u16* __restrict__ U,
                                              u16* __restrict__ Y, int skip, int doGelu){
  extern __shared__ u16 lds[];
  u16* sV  = lds;                    // 64 rows x 1024 u16, swizzled (131072 B)
  u16* sKR = lds + 65536;            // 8 copies x KRSW_ (17792 B)
  u16* sKt = lds + 65536 + 8*KRSW_;  // Kpad row tmp (2176 B)
  const bool bff = (*mk == MARK_BF16);
  int h = blockIdx.x;
  int tid = threadIdx.x;
  const u16* Kbh = Kb + h*KROW_;
  for (int s = tid; s < 1088; s += 1024) sKt[s] = Kbh[s];
  __syncthreads();
  #pragma unroll
  for (int p = 0; p < 8; ++p){
    for (int s = tid; s < KRSW_; s += 1024){
      int idx = 1087 - s - p;
      sKR[p*KRSW_ + s] = (idx >= 0) ? sKt[idx] : (u16)0;
    }
  }
  {
    const u16* Vh = V + (size_t)h*(B_*L_);
    #pragma unroll
    for (int q = 0; q < 8; ++q){
      int chunk = q*1024 + tid;       // 0..8191 16B-chunks
      int r = chunk >> 7;
      int c16 = chunk & 127;
      uint4 dval = *(const uint4*)(Vh + r*L_ + c16*8);
      u32 byte = ((u32)r << 11) + ((u32)c16 << 4);
      byte ^= ((u32)(r & 7) << 4);
      *(uint4*)((char*)sV + byte) = dval;
    }
  }
  __syncthreads();
  int c_out = tid >> 6, lane = tid & 63;
  int nl = lane & 15, quad = lane >> 4;
  float Dh = ld_in(Dv, dOff + h, bff);
  f32x4 acc[4][4];
  #pragma unroll
  for (int mt=0;mt<4;++mt){
    #pragma unroll
    for (int nt=0;nt<4;++nt) acc[mt][nt] = (f32x4){0.f,0.f,0.f,0.f};
  }
  for (int ci = 0; ci <= c_out; ++ci){
    int d = c_out - ci;
    short8 b0[4], b1[4];
    #pragma unroll
    for (int nt=0;nt<4;++nt){
      int i = nt*16 + nl;
      int t0 = 1023 - d*64 - i + quad*8;     // in [0,1054]
      const u16* bp = sKR + (t0 & 7)*KRSW_ + (t0 & ~7);
      b0[nt] = *(const short8*)bp;
      b1[nt] = *(const short8*)(bp + 32);
    }
    #pragma unroll
    for (int mt=0;mt<4;++mt){
      int r = mt*16 + nl;
      u32 msk = (u32)(r & 7) << 4;
      u32 base = ((u32)r << 11) + (u32)((ci*64 + quad*8) << 1);
      short8 a0 = *(const short8*)((const char*)sV + (base ^ msk));
      short8 a1 = *(const short8*)((const char*)sV + ((base + 64u) ^ msk));
      #pragma unroll
      for (int nt=0;nt<4;++nt){
        acc[mt][nt] = __builtin_amdgcn_mfma_f32_16x16x32_bf16(a0, b0[nt], acc[mt][nt], 0,0,0);
        acc[mt][nt] = __builtin_amdgcn_mfma_f32_16x16x32_bf16(a1, b1[nt], acc[mt][nt], 0,0,0);
      }
    }
  }
  #pragma unroll
  for (int mt=0;mt<4;++mt){
    #pragma unroll
    for (int reg=0;reg<4;++reg){
      int b = mt*16 + quad*4 + reg;
      if (b < B_){
        #pragma unroll
        for (int nt=0;nt<4;++nt){
          int col = c_out*64 + nt*16 + nl;
          u32 vb = (((u32)b << 11) + ((u32)col << 1)) ^ ((u32)(b & 7) << 4);
          float vv = u2f(*(const u16*)((const char*)sV + vb));
          size_t gi = (size_t)(h*B_ + b)*L_ + col;
          float y = tanh_f(acc[mt][nt][reg] + vv*Dh);
          if (skip) y += u2f(U[gi]);
          if (doGelu) y = gelu_f(y);
          Y[gi] = f2u(y);
        }
      }
    }
  }
}

// ---------------- MFMA FF v4: per block = 64-n stripe x ALL 512 m ----------------
__global__ __launch_bounds__(512, 4) void kFF2(const u32* __restrict__ mk,
                                            const u16* __restrict__ Yin, const u16* __restrict__ Wbt,
                                            const void* __restrict__ bias, u16* __restrict__ Zout,
                                            const u16* __restrict__ Zold, float* __restrict__ lossAcc,
                                            int doLoss){
  extern __shared__ char ldsF[];
  u16* res  = (u16*)(ldsF + FF_RES);      // [64][72] u16
  float* sb = (float*)(ldsF + FF_SB);     // bias[512]
  float* red= (float*)(ldsF + FF_RED);    // loss reduction[512]
  const bool bff = (*mk == MARK_BF16);
  int n0g = blockIdx.x*64;
  int tid = threadIdx.x;

  sb[tid & 511] = ld_in(bias, tid & 511, bff);

  // transpose Y (64 n x 512 k) into yt, swizzled
  {
    int rY = tid >> 3, q3 = tid & 7;
    #pragma unroll
    for (int kc=0;kc<8;++kc){
      const u16* yp = Yin + (size_t)(kc*64 + rY)*BL_ + n0g + q3*8;
      uint4 v = *(const uint4*)yp;
      const u16* pv = (const u16*)&v;
      int nb = q3*8;
      #pragma unroll
      for (int j=0;j<8;++j) *(u16*)(ldsF + YTB(kc, nb+j, rY*2)) = pv[j];
    }
  }
  __syncthreads();

  int wv = tid >> 6, lane = tid & 63;
  int nl = lane & 15, quad = lane >> 4;
  int mt = wv >> 1, ntb = (wv & 1)*2;
  int mrow = mt*16 + nl;
  int nr0 = ntb*16 + nl, nr1 = nr0 + 16;

  float ls = 0.f;
  int frow = tid >> 3, fcol = (tid & 7)*8;

  #pragma unroll 1
  for (int mc=0; mc<8; ++mc){
    f32x4 acc0 = (f32x4){0.f,0.f,0.f,0.f};
    f32x4 acc1 = (f32x4){0.f,0.f,0.f,0.f};
    const u16* wrow = Wbt + (size_t)(mc*64 + mrow)*512 + quad*8;
    #pragma unroll
    for (int kc=0;kc<8;++kc){
      short8 a0  = *(const short8*)(wrow + kc*64);          // L2-resident W
      short8 a1  = *(const short8*)(wrow + kc*64 + 32);
      short8 b00 = *(const short8*)(ldsF + YTB(kc, nr0, quad*16));
      short8 b01 = *(const short8*)(ldsF + YTB(kc, nr0, 64 + quad*16));
      short8 b10 = *(const short8*)(ldsF + YTB(kc, nr1, quad*16));
      short8 b11 = *(const short8*)(ldsF + YTB(kc, nr1, 64 + quad*16));
      acc0 = __builtin_amdgcn_mfma_f32_16x16x32_bf16(a0, b00, acc0, 0,0,0);
      acc0 = __builtin_amdgcn_mfma_f32_16x16x32_bf16(a1, b01, acc0, 0,0,0);
      acc1 = __builtin_amdgcn_mfma_f32_16x16x32_bf16(a0, b10, acc1, 0,0,0);
      acc1 = __builtin_amdgcn_mfma_f32_16x16x32_bf16(a1, b11, acc1, 0,0,0);
    }
    // epilogue -> res (per-wave disjoint regions)
    #pragma unroll
    for (int reg=0;reg<4;++reg){
      int mloc = mt*16 + quad*4 + reg;
      float bv = sb[mc*64 + mloc];
      res[mloc*72 + ntb*16 + nl]      = f2u(gelu_f(acc0[reg] + bv));
      res[mloc*72 + ntb*16 + nl + 16] = f2u(gelu_f(acc1[reg] + bv));
    }
    __syncthreads();   // res complete
    // flush: one full 128B line per 8-lane group
    {
      size_t zoff = (size_t)(mc*64 + frow)*BL_ + n0g + fcol;
      uint4 v = *(const uint4*)&res[frow*72 + fcol];
      if (doLoss){
        uint4 zo = *(const uint4*)(Zold + zoff);
        const u16* pv = (const u16*)&v;
        const u16* po = (const u16*)&zo;
        #pragma unroll
        for (int j=0;j<8;++j){ float d = u2f(pv[j]) - u2f(po[j]); ls += d*d; }
      }
      *(uint4*)(Zout + zoff) = v;
    }
    __syncthreads();   // res free for next epilogue
  }
  if (doLoss){
    red[tid] = ls;
    __syncthreads();
    for (int off=256; off>0; off>>=1){
      if (tid < off) red[tid] += red[tid+off];
      __syncthreads();
    }
    if (tid==0) atomicAdd(lossAcc, red[0]);
  }
}

// ---------------- scalars: loss + n_deq (f32 out) ----------------
__global__ void kScalars(const float* __restrict__ lossAcc, float* __restrict__ outp){
  if (threadIdx.x == 0 && blockIdx.x == 0){
    outp[500] = *lossAcc * (1.f/26214400.f);
    outp[26214901] = 8.0f;
  }
}

// ---------------- transpose [H,B,L] bf16 -> out[b,l,h] f32 ----------------
__global__ __launch_bounds__(256) void kTrans(const u16* __restrict__ Z, float* __restrict__ out){
  __shared__ u16 st[64][68];
  int b = blockIdx.z, h0 = blockIdx.y*64, l0 = blockIdx.x*64;
  int tid = threadIdx.x;
  int r = tid >> 2, q = tid & 3;
  const u16* src = Z + ((h0+r)*B_ + b)*L_ + l0 + q*16;
  #pragma unroll
  for (int c=0; c<4; ++c){
    ushort4 v = *(const ushort4*)(src + c*4);
    st[r][q*16 + c*4 + 0] = v.x;
    st[r][q*16 + c*4 + 1] = v.y;
    st[r][q*16 + c*4 + 2] = v.z;
    st[r][q*16 + c*4 + 3] = v.w;
  }
  __syncthreads();
  int i = tid & 63;
  int j0 = tid >> 6;
  for (int jj = j0; jj < 64; jj += 4){
    out[(size_t)(b*L_ + l0 + jj)*H_ + h0 + i] = u2f(st[i][jj]);
  }
}

// ---------------- mean over l ----------------
__global__ __launch_bounds__(256) void kMeanL(const u16* __restrict__ Z, float* __restrict__ Hb){
  int lane = threadIdx.x & 63;
  int ridx = blockIdx.x*4 + (threadIdx.x >> 6);  // = ho*B_+b
  const u16* row = Z + (size_t)ridx*L_;
  float s = 0.f;
  for (int ii=lane; ii<L_; ii+=64) s += u2f(row[ii]);
  for (int off=32; off>0; off>>=1) s += __shfl_down(s, off, 64);
  if (lane==0){
    int ho = ridx / B_, b = ridx - ho*B_;
    Hb[b*H_ + ho] = s*(1.f/1024.f);
  }
}

__global__ __launch_bounds__(256) void kLogits(const u32* __restrict__ mk,
                                               const float* __restrict__ Hb, const void* __restrict__ Wfc,
                                               const void* __restrict__ bfc, float* __restrict__ outp){
  const bool bff = (*mk == MARK_BF16);
  int t = blockIdx.x*256 + threadIdx.x;
  if (t < 500){
    int b = t/10, c = t - (t/10)*10;
    float s = ld_in(bfc, c, bff);
    for (int ho=0; ho<H_; ++ho) s += Hb[b*H_+ho]*ld_in(Wfc, ho*10+c, bff);
    outp[t] = s;
  }
}

extern "C" void kernel_launch(void* const* d_in, const int* in_sizes, int n_in,
                              void* d_out, int out_size, void* d_ws, size_t ws_size,
                              hipStream_t stream) {
  (void)in_sizes; (void)n_in; (void)out_size; (void)ws_size;
  const void* x      = d_in[0];
  const void* W_emb  = d_in[1];
  const void* b_emb  = d_in[2];
  const void* C_re   = d_in[3];
  const void* C_im   = d_in[4];
  const void* Dp     = d_in[5];
  const void* ln_g   = d_in[6];
  const void* ln_b   = d_in[7];
  const void* W_feed = d_in[8];
  const void* b_feed = d_in[9];
  const void* W_fc   = d_in[10];
  const void* b_fc   = d_in[11];
  const u32* mk = (const u32*)d_in[5];
  float* outp = (float*)d_out;

  static int s_attr = 0;
  if (!s_attr){
    hipFuncSetAttribute(reinterpret_cast<const void*>(kConvM),
                        hipFuncAttributeMaxDynamicSharedMemorySize, CONV_LDS_BYTES);
    hipFuncSetAttribute(reinterpret_cast<const void*>(kFF2),
                        hipFuncAttributeMaxDynamicSharedMemorySize, FF2_LDS_BYTES);
    s_attr = 1;
  }

  // ws: Kbp bf16[6*512*1088] | Zb | T1 | T2 (bf16 HBL each) | Hbar f32 | lossAcc | Wbt (~164.6 MB)
  u16* Kbp = (u16*)d_ws;
  u16* Zb  = Kbp + 6*H_*KROW_;
  u16* T1  = Zb + HBL_;
  u16* T2  = T1 + HBL_;
  float* Hbar = (float*)(T2 + HBL_);
  float* lossAcc = Hbar + 25600;
  u16* Wbt = (u16*)(Hbar + 25604);               // 0.5 MB, 16B-aligned
  // d_out-resident scratch: X0 (bf16 HBL, bytes 0..52.4MB); dead before final writes.
  u16* X0  = (u16*)d_out;
  // phase-A f32 scratch carved from T1
  float* Vre = (float*)T1;
  float* Vim = Vre + N_*L_;
  float* Xre = Vim + N_*L_;
  float* Xim = Xre + 6*H_*N_;

  // 1) kernels K (bf16 padded) + W transpose
  kV<<<2048, 256, 0, stream>>>(Vre, Vim);
  kX<<<6144, 256, 0, stream>>>(mk, C_re, C_im, Xre, Xim);
  kK<<<dim3(384,2), 256, 0, stream>>>(Xre, Xim, Vre, Vim, Kbp);
  kWb<<<1024, 256, 0, stream>>>(mk, W_feed, Wbt);

  // 2) embedding -> X0
  kEmbed<<<25600, 256, 0, stream>>>(mk, x, W_emb, b_emb, X0);

  // 3) three explicit S4D blocks, out-of-place ping-pong X0 <-> T2
  u16* cur = X0;
  u16* nxt = T2;
  for (int i=0;i<3;++i){
    kLN2<<<800,256,0,stream>>>(mk, cur, nullptr, ln_g, ln_b, i*H_, T1);
    kConvM<<<512, 1024, CONV_LDS_BYTES, stream>>>(mk, T1, Kbp + i*H_*KROW_, Dp, i*H_, cur, nxt, 1, 0);
    u16* tmp = cur; cur = nxt; nxt = tmp;
  }
  u16* XINJ = cur;                         // T2
  u16* BT   = nxt;                         // X0: DEQ bounce buffer

  // 4) DEQ: z=0; 8 applications of f
  kZero<<<12800, 256, 0, stream>>>((uint4*)Zb, lossAcc);
  for (int it=0; it<8; ++it){
    int last = (it == 7);
    kLN2<<<800,256,0,stream>>>(mk, Zb, XINJ, ln_g, ln_b, 3*H_, T1);
    kConvM<<<512, 1024, CONV_LDS_BYTES, stream>>>(mk, T1, Kbp + 3*H_*KROW_, Dp, 3*H_, nullptr, BT, 0, 0);
    kLN2<<<800,256,0,stream>>>(mk, BT, nullptr, ln_g, ln_b, 4*H_, T1);
    kConvM<<<512, 1024, CONV_LDS_BYTES, stream>>>(mk, T1, Kbp + 4*H_*KROW_, Dp, 4*H_, nullptr, BT, 0, 0);
    kLN2<<<800,256,0,stream>>>(mk, BT, nullptr, ln_g, ln_b, 5*H_, T1);
    kConvM<<<512, 1024, CONV_LDS_BYTES, stream>>>(mk, T1, Kbp + 5*H_*KROW_, Dp, 5*H_, nullptr, BT, 0, 1);
    kFF2<<<800, 512, FF2_LDS_BYTES, stream>>>(mk, BT, Wbt, b_feed, Zb, Zb, lossAcc, last);
  }

  // 5) outputs (X0/XINJ dead; d_out safe to finalize as f32)
  kMeanL<<<6400,256,0,stream>>>(Zb, Hbar);
  kScalars<<<1, 64, 0, stream>>>(lossAcc, outp);
  kTrans<<<dim3(16,8,50),256,0,stream>>>(Zb, outp + 501);
  kLogits<<<2,256,0,stream>>>(mk, Hbar, W_fc, b_fc, outp);
}